// Round 1
// baseline (801.607 us; speedup 1.0000x reference)
//
#include <hip/hip_runtime.h>
#include <math.h>
#include <stdint.h>

// NeuralMJP forward, MI355X/gfx950.
// Key facts exploited:
//  * sample == one-hot(argmax(logits)) exactly in the forward pass
//    -> decoder collapses to a 32x32 table lookup (prep kernel).
//  * argmax(softmax(z)) == argmax(z) -> y never materialized.
//  * fp32 only (no fp32 MFMA on CDNA4; bf16 would flip Gumbel argmaxes).
//  * Weights are wave-uniform -> packed so the compiler emits s_load
//    (scalar pipe), keeping VALU free for the 24576 FMAs/element.

constexpr int kB = 524288;  // batch
constexpr int kD = 32;      // input dim
constexpr int kH = 128;     // hidden
constexpr int kS = 32;      // states

// -------- prep: pack weights + build decoder table ------------------------
// pw layout: [p][j][0..31] = w1_p[i][j] (transposed col), [p][j][32..63] = w2_p[j][s]
__global__ __launch_bounds__(1024) void prep_kernel(
    const float* __restrict__ q_w1,  const float* __restrict__ q_w2,
    const float* __restrict__ gi_w1, const float* __restrict__ gi_w2,
    const float* __restrict__ go_w1, const float* __restrict__ go_w2,
    const float* __restrict__ dec_w1, const float* __restrict__ dec_b1,
    const float* __restrict__ dec_w2, const float* __restrict__ dec_b2,
    float* __restrict__ pw, float* __restrict__ table)
{
    const int t = threadIdx.x;
    // decoder table: row k = relu(dec_w1[k,:] + dec_b1) @ dec_w2 + dec_b2
    {
        const int k = t >> 5, d = t & 31;
        float acc = 0.0f;
        #pragma unroll 4
        for (int j = 0; j < kH; ++j) {
            float a = dec_w1[k * kH + j] + dec_b1[j];
            a = fmaxf(a, 0.0f);
            acc = fmaf(a, dec_w2[j * kS + d], acc);
        }
        table[k * kS + d] = acc + dec_b2[d];
    }
    // weight packing: 3*128 rows of 64 floats
    if (t < 3 * kH) {
        const int p = t >> 7;
        const int j = t & (kH - 1);
        const float* w1 = (p == 0) ? q_w1 : (p == 1) ? gi_w1 : go_w1;
        const float* w2 = (p == 0) ? q_w2 : (p == 1) ? gi_w2 : go_w2;
        float* row = pw + (size_t)(p * kH + j) * 64;
        for (int i = 0; i < kD; ++i) row[i] = w1[i * kH + j];
        for (int s = 0; s < kS; ++s) row[32 + s] = w2[j * kS + s];
    }
}

// -------- main ------------------------------------------------------------
__device__ __forceinline__ void mlp_pass(const float* __restrict__ hv,
                                         const float* __restrict__ wbase,
                                         const float* __restrict__ b1,
                                         const float* __restrict__ b2,
                                         float* __restrict__ lg)
{
    #pragma unroll
    for (int s = 0; s < kS; ++s) lg[s] = 0.0f;
    #pragma unroll 1
    for (int j = 0; j < kH; ++j) {   // rolled: body ~80 instrs, stays in I$
        const float* __restrict__ wr = wbase + j * 64;  // wave-uniform -> s_load
        float a0 = 0.f, a1 = 0.f, a2 = 0.f, a3 = 0.f;
        #pragma unroll
        for (int i = 0; i < 8; ++i) {   // 4 chains: break fma latency serialization
            a0 = fmaf(hv[i],      wr[i],      a0);
            a1 = fmaf(hv[i + 8],  wr[i + 8],  a1);
            a2 = fmaf(hv[i + 16], wr[i + 16], a2);
            a3 = fmaf(hv[i + 24], wr[i + 24], a3);
        }
        float a = ((a0 + a1) + (a2 + a3)) + b1[j];  // dot first, then bias (matches np)
        a = fmaxf(a, 0.0f);
        #pragma unroll
        for (int s = 0; s < kS; ++s) lg[s] = fmaf(a, wr[32 + s], lg[s]);
    }
    #pragma unroll
    for (int s = 0; s < kS; ++s) lg[s] += b2[s];
}

__device__ __forceinline__ float tree_sum32(const float* __restrict__ v)
{
    float b0 = 0.f, b1 = 0.f, b2 = 0.f, b3 = 0.f;
    #pragma unroll
    for (int i = 0; i < 8; ++i) {
        b0 += v[i]; b1 += v[i + 8]; b2 += v[i + 16]; b3 += v[i + 24];
    }
    return (b0 + b1) + (b2 + b3);   // pairwise-ish, like np.sum
}

__device__ __forceinline__ void softmax32(const float* __restrict__ lg,
                                          float* __restrict__ p)
{
    float m = lg[0];
    #pragma unroll
    for (int s = 1; s < kS; ++s) m = fmaxf(m, lg[s]);
    float e[kS];
    #pragma unroll
    for (int s = 0; s < kS; ++s) e[s] = expf(lg[s] - m);
    const float Z = tree_sum32(e);
    #pragma unroll
    for (int s = 0; s < kS; ++s) p[s] = e[s] / Z;  // precise div, like np
}

__global__ __launch_bounds__(256) void main_kernel(
    const float* __restrict__ h, const float* __restrict__ u,
    const float* __restrict__ qb1, const float* __restrict__ qb2,
    const float* __restrict__ gib1, const float* __restrict__ gib2,
    const float* __restrict__ gob1, const float* __restrict__ gob2,
    const float* __restrict__ pw, const float* __restrict__ table,
    float* __restrict__ out)
{
    const int b = blockIdx.x * 256 + threadIdx.x;

    float hv[kD];
    {
        const float4* h4 = reinterpret_cast<const float4*>(h + (size_t)b * kD);
        #pragma unroll
        for (int i = 0; i < 8; ++i) {
            float4 t = h4[i];
            hv[4 * i + 0] = t.x; hv[4 * i + 1] = t.y;
            hv[4 * i + 2] = t.z; hv[4 * i + 3] = t.w;
        }
    }

    float lg[kS], q[kS], gi[kS];

    mlp_pass(hv, pw,               qb1,  qb2,  lg);
    softmax32(lg, q);
    mlp_pass(hv, pw + 1 * kH * 64, gib1, gib2, lg);
    softmax32(lg, gi);
    mlp_pass(hv, pw + 2 * kH * 64, gob1, gob2, lg);

    // g_out softmax fused with gumbel argmax (y never materialized)
    float m3 = lg[0];
    #pragma unroll
    for (int s = 1; s < kS; ++s) m3 = fmaxf(m3, lg[s]);
    float e3[kS];
    #pragma unroll
    for (int s = 0; s < kS; ++s) e3[s] = expf(lg[s] - m3);
    const float Z3 = tree_sum32(e3);
    const float qs = tree_sum32(q);   // == sum(q), ~1, computed like the reference

    float uv[kS];
    {
        const float4* u4 = reinterpret_cast<const float4*>(u + (size_t)b * kS);
        #pragma unroll
        for (int i = 0; i < 8; ++i) {
            float4 t = u4[i];
            uv[4 * i + 0] = t.x; uv[4 * i + 1] = t.y;
            uv[4 * i + 2] = t.z; uv[4 * i + 3] = t.w;
        }
    }

    float best = -__builtin_inff();
    int bi = 0;
    {
        #pragma clang fp contract(off)   // match np's per-op rounding here
        #pragma unroll
        for (int s = 0; s < kS; ++s) {
            const float gos = e3[s] / Z3;
            const float t1 = gi[s] * (qs - q[s]);
            const float t2 = gos * q[s];
            const float qn = q[s] + (t1 + t2);
            const float gn = -logf(-logf(uv[s] + 1e-20f) + 1e-20f);
            const float v  = logf(qn + 1e-12f) + gn;
            if (v > best) { best = v; bi = s; }   // strict >: first-index ties, like np.argmax
        }
    }

    // out[b,:] = table[bi,:]
    const float4* trow = reinterpret_cast<const float4*>(table + (size_t)bi * kS);
    float4* orow = reinterpret_cast<float4*>(out + (size_t)b * kD);
    #pragma unroll
    for (int i = 0; i < 8; ++i) orow[i] = trow[i];
}

extern "C" void kernel_launch(void* const* d_in, const int* in_sizes, int n_in,
                              void* d_out, int out_size, void* d_ws, size_t ws_size,
                              hipStream_t stream)
{
    const float* h      = (const float*)d_in[0];
    const float* u      = (const float*)d_in[1];
    const float* q_w1   = (const float*)d_in[2];
    const float* q_b1   = (const float*)d_in[3];
    const float* q_w2   = (const float*)d_in[4];
    const float* q_b2   = (const float*)d_in[5];
    const float* gi_w1  = (const float*)d_in[6];
    const float* gi_b1  = (const float*)d_in[7];
    const float* gi_w2  = (const float*)d_in[8];
    const float* gi_b2  = (const float*)d_in[9];
    const float* go_w1  = (const float*)d_in[10];
    const float* go_b1  = (const float*)d_in[11];
    const float* go_w2  = (const float*)d_in[12];
    const float* go_b2  = (const float*)d_in[13];
    const float* dec_w1 = (const float*)d_in[14];
    const float* dec_b1 = (const float*)d_in[15];
    const float* dec_w2 = (const float*)d_in[16];
    const float* dec_b2 = (const float*)d_in[17];

    float* pw    = (float*)d_ws;                      // 3*128*64*4 = 98304 B
    float* table = (float*)((char*)d_ws + 98304);     // 32*32*4    =  4096 B
    float* out   = (float*)d_out;

    prep_kernel<<<1, 1024, 0, stream>>>(q_w1, q_w2, gi_w1, gi_w2, go_w1, go_w2,
                                        dec_w1, dec_b1, dec_w2, dec_b2, pw, table);
    main_kernel<<<kB / 256, 256, 0, stream>>>(h, u, q_b1, q_b2, gi_b1, gi_b2,
                                              go_b1, go_b2, pw, table, out);
}